// Round 1
// baseline (44.454 us; speedup 1.0000x reference)
//
#include <hip/hip_runtime.h>

#define B_TOTAL 4194304
#define NBLK 1024
#define NTHR 256

__device__ __forceinline__ float fast_tanh(float x) {
    // stable: e in (0,1], no overflow; ~1e-7 abs error vs libm tanhf
    float ax = fabsf(x);
    float e  = __expf(-2.0f * ax);
    float t  = (1.0f - e) / (1.0f + e);
    return copysignf(t, x);
}

__device__ __forceinline__ void norm_sc(float s, float c, float& S, float& C) {
    float r2 = fmaf(s, s, c * c);
    if (r2 > 1e-20f) {
        float iv = rsqrtf(r2);
        S = s * iv; C = c * iv;
    } else {            // atan2(0,0) == 0  ->  sin=0, cos=1
        S = 0.0f; C = 1.0f;
    }
}

__global__ __launch_bounds__(NTHR) void ik_loss_partial(
    const float* __restrict__ pred_raw,
    const float* __restrict__ target_sc,
    const float* __restrict__ p5t,
    double* __restrict__ partial)
{
    // PUMA560 constants
    const float d1 = 671.83f, a2 = 431.8f, d2 = 139.7f, a3 = -20.32f, D4 = 431.8f;
    const float inv_r = 1.0f / 900.0f;

    float acc_sc = 0.f, acc_wc = 0.f, acc_circ = 0.f;

    const int stride = NBLK * NTHR;
    for (int i = blockIdx.x * NTHR + threadIdx.x; i < B_TOTAL; i += stride) {
        const size_t r6 = 6 * (size_t)i;
        const size_t r3 = 3 * (size_t)i;
        // rows are 24B -> float2 loads are 8B-aligned
        const float2* pr = (const float2*)(pred_raw + r6);
        const float2* tg = (const float2*)(target_sc + r6);
        float2 p01 = pr[0], p23 = pr[1], p45 = pr[2];
        float2 t01 = tg[0], t23 = tg[1], t45 = tg[2];
        float q0 = p5t[r3 + 0], q1 = p5t[r3 + 1], q2 = p5t[r3 + 2];

        // tanh -> predicted sin/cos pairs (cols 0,2,4 = sin; 1,3,5 = cos)
        float s1 = fast_tanh(p01.x), c1 = fast_tanh(p01.y);
        float s2 = fast_tanh(p23.x), c2 = fast_tanh(p23.y);
        float s3 = fast_tanh(p45.x), c3 = fast_tanh(p45.y);

        // loss_sc: sum of squared diffs over all 6 comps
        float d;
        d = s1 - t01.x; acc_sc += d * d;
        d = c1 - t01.y; acc_sc += d * d;
        d = s2 - t23.x; acc_sc += d * d;
        d = c2 - t23.y; acc_sc += d * d;
        d = s3 - t45.x; acc_sc += d * d;
        d = c3 - t45.y; acc_sc += d * d;

        // loss_circ: (s^2+c^2-1)^2 per joint
        float r21 = fmaf(s1, s1, c1 * c1);
        float r22 = fmaf(s2, s2, c2 * c2);
        float r23 = fmaf(s3, s3, c3 * c3);
        d = r21 - 1.0f; acc_circ += d * d;
        d = r22 - 1.0f; acc_circ += d * d;
        d = r23 - 1.0f; acc_circ += d * d;

        // normalized sin/cos == sin/cos(atan2(s,c)); deg<->rad roundtrip is identity
        float S1, C1, S2, C2, S3, C3;
        norm_sc(s1, c1, S1, C1);
        norm_sc(s2, c2, S2, C2);
        norm_sc(s3, c3, S3, C3);

        // closed-form P5 = T03[:, :3, 3] + D4 * T03[:, :3, 2]
        float s23 = fmaf(S2, C3, C2 * S3);
        float c23 = fmaf(C2, C3, -S2 * S3);
        float pxp = fmaf(a3, c23, a2 * C2) + D4 * s23;   // px' + D4*s23
        float x = fmaf(C1, pxp, -S1 * d2);
        float y = fmaf(S1, pxp,  C1 * d2);
        float z = d1 - fmaf(a3, s23, a2 * S2) + D4 * c23;

        float dx = (x - q0) * inv_r;
        float dy = (y - q1) * inv_r;
        float dz = (z - q2) * inv_r;
        acc_wc += fmaf(dx, dx, fmaf(dy, dy, dz * dz));
    }

    // weighted combine in double, deterministic block reduce
    const double k_sc = 1.0  / (6.0 * (double)B_TOTAL);
    const double k_wc = 2.0  / (3.0 * (double)B_TOTAL);
    const double k_ci = 0.05 / (3.0 * (double)B_TOTAL);
    double v = (double)acc_sc * k_sc + (double)acc_wc * k_wc + (double)acc_circ * k_ci;

    #pragma unroll
    for (int off = 32; off > 0; off >>= 1) v += __shfl_down(v, off, 64);

    __shared__ double sm[NTHR / 64];
    int lane = threadIdx.x & 63, w = threadIdx.x >> 6;
    if (lane == 0) sm[w] = v;
    __syncthreads();
    if (threadIdx.x == 0) {
        double t = 0.0;
        #pragma unroll
        for (int j = 0; j < NTHR / 64; ++j) t += sm[j];
        partial[blockIdx.x] = t;
    }
}

__global__ __launch_bounds__(NTHR) void ik_loss_final(
    const double* __restrict__ partial, float* __restrict__ out)
{
    double v = 0.0;
    for (int i = threadIdx.x; i < NBLK; i += NTHR) v += partial[i];
    #pragma unroll
    for (int off = 32; off > 0; off >>= 1) v += __shfl_down(v, off, 64);

    __shared__ double sm[NTHR / 64];
    int lane = threadIdx.x & 63, w = threadIdx.x >> 6;
    if (lane == 0) sm[w] = v;
    __syncthreads();
    if (threadIdx.x == 0) {
        double t = 0.0;
        #pragma unroll
        for (int j = 0; j < NTHR / 64; ++j) t += sm[j];
        out[0] = (float)t;
    }
}

extern "C" void kernel_launch(void* const* d_in, const int* in_sizes, int n_in,
                              void* d_out, int out_size, void* d_ws, size_t ws_size,
                              hipStream_t stream) {
    const float* pred_raw  = (const float*)d_in[0];
    const float* target_sc = (const float*)d_in[1];
    const float* p5_target = (const float*)d_in[2];
    double* partial = (double*)d_ws;          // NBLK doubles = 8 KiB
    float*  out     = (float*)d_out;

    ik_loss_partial<<<NBLK, NTHR, 0, stream>>>(pred_raw, target_sc, p5_target, partial);
    ik_loss_final<<<1, NTHR, 0, stream>>>(partial, out);
}